// Round 3
// baseline (2424.230 us; speedup 1.0000x reference)
//
#include <hip/hip_runtime.h>
#include <math.h>

// WaveNet on MI355X — round 3.
// R2 forensics: 30us/layer vs ~7us FMA floor. Suspect: weight fetch path
// (per-lane L1 loads if scalarization didn't fire, or s_load lgkmcnt waits).
// Fix: stage weights in LDS (broadcast ds_read, off the VALU path) and
// process 2 far-split timesteps per thread (same t, batches b and b+2) so
// each weight read feeds 64 FMAs. 512 blocks x 256 thr, ~200 VGPR, 7.5KB LDS.

constexpr int TL = 65536;    // T
constexpr int HALF = 131072; // thread j handles g=j and g=j+HALF

// ---------------- weight packing ----------------
// conv_w/gate_w [18][o=16][i=16][k=3] -> packed [18][k=3][i=16][o=16]  (o fastest)
// res_w [17][o=16][i=16] -> [17][i=16][o=16]
// layer-0 folded with start_w: e0f[k][o] = sum_i conv_w[0][o][i][k]*start_w[i]
__global__ __launch_bounds__(256) void pack_kernel(
    const float* __restrict__ start_w,
    const float* __restrict__ conv_w,
    const float* __restrict__ gate_w,
    const float* __restrict__ res_w,
    float* __restrict__ wf, float* __restrict__ wg,
    float* __restrict__ rw, float* __restrict__ e0f, float* __restrict__ e0g)
{
    int idx = blockIdx.x * 256 + threadIdx.x;
    if (idx < 13824) {
        int li = idx / 768;
        int r  = idx % 768;
        int k  = r / 256;
        int i  = (r / 16) % 16;
        int o  = r % 16;
        int src = ((li * 16 + o) * 16 + i) * 3 + k;
        wf[idx] = conv_w[src];
        wg[idx] = gate_w[src];
    } else if (idx < 13824 + 4352) {
        int j  = idx - 13824;
        int li = j / 256;
        int r  = j % 256;
        int i  = r / 16;
        int o  = r % 16;
        rw[j] = res_w[(li * 16 + o) * 16 + i];
    } else if (idx < 13824 + 4352 + 96) {
        int j = idx - 13824 - 4352;   // [0,96): 48 for f, 48 for g
        int which = j / 48;
        int r = j % 48;
        int k = r / 16;
        int o = r % 16;
        const float* src = which ? gate_w : conv_w;
        float s = 0.f;
        #pragma unroll
        for (int i = 0; i < 16; ++i) s += src[(o * 16 + i) * 3 + k] * start_w[i];
        (which ? e0g : e0f)[k * 16 + o] = s;
    }
}

__device__ __forceinline__ float softsign_f(float v) {
    return v * __builtin_amdgcn_rcpf(1.0f + fabsf(v));
}

// ---------------- fused layer kernel ----------------
// MODE 0: first layer (x via folded start conv; writes h_out, skip=)
// MODE 1: middle layer (reads h_in, writes h_out, skip+=)
// MODE 2: last layer (reads h_in, no residual, out = skip + contribution)
// lbias layout: [0:16) conv_b  [16:32) gate_b  [32:48) res_b  [48:64) mixer
//               [64:80) start_w (MODE 0 only)
template <int MODE>
__global__ __launch_bounds__(256, 2) void layer_kernel(
    const float* __restrict__ x,
    const float* __restrict__ start_w,
    const float* __restrict__ h_in,
    float* __restrict__ h_out,
    const float* __restrict__ wf,   // MODE0: e0f[3][16]; else packed [3][16][16]
    const float* __restrict__ cb,
    const float* __restrict__ wg,
    const float* __restrict__ gb,
    const float* __restrict__ rw,   // packed [i][o], MODE 0/1
    const float* __restrict__ rb,
    const float* __restrict__ mx,   // mixer row slice for this layer [16]
    float* __restrict__ skip,
    float* __restrict__ out,
    int d)
{
    __shared__ float lwf[768];
    __shared__ float lwg[768];
    __shared__ float lrw[256];
    __shared__ float lbias[80];

    const int td = threadIdx.x;
    const int j  = blockIdx.x * 256 + td;     // j in [0, HALF)
    const int t  = j & (TL - 1);

    // ---- stage weights into LDS ----
    if (MODE == 0) {
        if (td < 48) { lwf[td] = wf[td]; lwg[td] = wg[td]; }
        lrw[td] = rw[td];
        if (td < 16)      lbias[td]      = cb[td];
        else if (td < 32) lbias[td]      = gb[td - 16];
        else if (td < 48) lbias[td]      = rb[td - 32];
        else if (td < 64) lbias[td]      = mx[td - 48];
        else if (td < 80) lbias[td]      = start_w[td - 64];
    } else {
        #pragma unroll
        for (int r = 0; r < 3; ++r) {
            lwf[td + r * 256] = wf[td + r * 256];
            lwg[td + r * 256] = wg[td + r * 256];
        }
        if (MODE == 1) lrw[td] = rw[td];
        if (td < 16)      lbias[td] = cb[td];
        else if (td < 32) lbias[td] = gb[td - 16];
        else if (td < 48) lbias[td] = (MODE == 1) ? rb[td - 32] : 0.f;
        else if (td < 64) lbias[td] = mx[td - 48];
    }
    __syncthreads();

    float f0[16], q0[16], f1[16], q1[16];
    #pragma unroll
    for (int o = 0; o < 16; ++o) {
        f0[o] = lbias[o];      f1[o] = f0[o];
        q0[o] = lbias[16 + o]; q1[o] = q0[o];
    }

    float zA[16], zB[16];
    float hcA[16], hcB[16];   // h at tap t (for residual)

    if (MODE == 0) {
        float xA2 = x[j];
        float xA1 = (t >= 1) ? x[j - 1] : 0.f;
        float xA0 = (t >= 2) ? x[j - 2] : 0.f;
        float xB2 = x[j + HALF];
        float xB1 = (t >= 1) ? x[j + HALF - 1] : 0.f;
        float xB0 = (t >= 2) ? x[j + HALF - 2] : 0.f;
        float xsA[3] = {xA0, xA1, xA2};
        float xsB[3] = {xB0, xB1, xB2};
        #pragma unroll
        for (int k = 0; k < 3; ++k) {
            float va = xsA[k], vb = xsB[k];
            #pragma unroll
            for (int o = 0; o < 16; ++o) {
                f0[o] += lwf[k * 16 + o] * va;
                f1[o] += lwf[k * 16 + o] * vb;
                q0[o] += lwg[k * 16 + o] * va;
                q1[o] += lwg[k * 16 + o] * vb;
            }
        }
        #pragma unroll
        for (int o = 0; o < 16; ++o) {
            hcA[o] = lbias[64 + o] * xA2;
            hcB[o] = lbias[64 + o] * xB2;
        }
    } else {
        // ---- prefetch all 6 tap vectors (96 floats) ----
        float tA[3][16], tB[3][16];
        const float* hpA = h_in + (size_t)j * 16;
        const float* hpB = h_in + ((size_t)j + HALF) * 16;
        #pragma unroll
        for (int k = 0; k < 3; ++k) {
            const int off = (k - 2) * d;
            const bool ok = (t + off) >= 0;
            const float4* pA = (const float4*)(hpA + (ptrdiff_t)off * 16);
            const float4* pB = (const float4*)(hpB + (ptrdiff_t)off * 16);
            #pragma unroll
            for (int q = 0; q < 4; ++q) {
                float4 a = ok ? pA[q] : make_float4(0.f, 0.f, 0.f, 0.f);
                float4 b = ok ? pB[q] : make_float4(0.f, 0.f, 0.f, 0.f);
                tA[k][q * 4 + 0] = a.x; tA[k][q * 4 + 1] = a.y;
                tA[k][q * 4 + 2] = a.z; tA[k][q * 4 + 3] = a.w;
                tB[k][q * 4 + 0] = b.x; tB[k][q * 4 + 1] = b.y;
                tB[k][q * 4 + 2] = b.z; tB[k][q * 4 + 3] = b.w;
            }
        }

        // ---- conv: LDS-broadcast weights, 64 FMAs per weight row ----
        const float4* w4f = (const float4*)lwf;
        const float4* w4g = (const float4*)lwg;
        #pragma unroll
        for (int k = 0; k < 3; ++k) {
            #pragma unroll
            for (int i = 0; i < 16; ++i) {
                const int ki = k * 16 + i;
                float wfr[16], wgr[16];
                *(float4*)&wfr[0]  = w4f[ki * 4 + 0];
                *(float4*)&wfr[4]  = w4f[ki * 4 + 1];
                *(float4*)&wfr[8]  = w4f[ki * 4 + 2];
                *(float4*)&wfr[12] = w4f[ki * 4 + 3];
                *(float4*)&wgr[0]  = w4g[ki * 4 + 0];
                *(float4*)&wgr[4]  = w4g[ki * 4 + 1];
                *(float4*)&wgr[8]  = w4g[ki * 4 + 2];
                *(float4*)&wgr[12] = w4g[ki * 4 + 3];
                const float va = tA[k][i], vb = tB[k][i];
                #pragma unroll
                for (int o = 0; o < 16; ++o) {
                    f0[o] += wfr[o] * va;
                    f1[o] += wfr[o] * vb;
                    q0[o] += wgr[o] * va;
                    q1[o] += wgr[o] * vb;
                }
            }
        }
        #pragma unroll
        for (int o = 0; o < 16; ++o) { hcA[o] = tA[2][o]; hcB[o] = tB[2][o]; }
    }

    #pragma unroll
    for (int o = 0; o < 16; ++o) {
        zA[o] = softsign_f(f0[o]) * softsign_f(q0[o]);
        zB[o] = softsign_f(f1[o]) * softsign_f(q1[o]);
    }

    float sA = 0.f, sB = 0.f;
    #pragma unroll
    for (int o = 0; o < 16; ++o) {
        sA += lbias[48 + o] * zA[o];
        sB += lbias[48 + o] * zB[o];
    }

    if (MODE == 0) {
        skip[j] = sA;  skip[j + HALF] = sB;
    } else if (MODE == 1) {
        skip[j] += sA; skip[j + HALF] += sB;
    } else {
        out[j] = skip[j] + sA;
        out[j + HALF] = skip[j + HALF] + sB;
    }

    if (MODE != 2) {
        float hnA[16], hnB[16];
        #pragma unroll
        for (int o = 0; o < 16; ++o) {
            hnA[o] = hcA[o] + lbias[32 + o];
            hnB[o] = hcB[o] + lbias[32 + o];
        }
        const float4* r4 = (const float4*)lrw;
        #pragma unroll
        for (int i = 0; i < 16; ++i) {
            float rr[16];
            *(float4*)&rr[0]  = r4[i * 4 + 0];
            *(float4*)&rr[4]  = r4[i * 4 + 1];
            *(float4*)&rr[8]  = r4[i * 4 + 2];
            *(float4*)&rr[12] = r4[i * 4 + 3];
            const float va = zA[i], vb = zB[i];
            #pragma unroll
            for (int o = 0; o < 16; ++o) {
                hnA[o] += rr[o] * va;
                hnB[o] += rr[o] * vb;
            }
        }
        float4* qA = (float4*)(h_out + (size_t)j * 16);
        float4* qB = (float4*)(h_out + ((size_t)j + HALF) * 16);
        qA[0] = make_float4(hnA[0],  hnA[1],  hnA[2],  hnA[3]);
        qA[1] = make_float4(hnA[4],  hnA[5],  hnA[6],  hnA[7]);
        qA[2] = make_float4(hnA[8],  hnA[9],  hnA[10], hnA[11]);
        qA[3] = make_float4(hnA[12], hnA[13], hnA[14], hnA[15]);
        qB[0] = make_float4(hnB[0],  hnB[1],  hnB[2],  hnB[3]);
        qB[1] = make_float4(hnB[4],  hnB[5],  hnB[6],  hnB[7]);
        qB[2] = make_float4(hnB[8],  hnB[9],  hnB[10], hnB[11]);
        qB[3] = make_float4(hnB[12], hnB[13], hnB[14], hnB[15]);
    }
}

extern "C" void kernel_launch(void* const* d_in, const int* in_sizes, int n_in,
                              void* d_out, int out_size, void* d_ws, size_t ws_size,
                              hipStream_t stream) {
    const float* x       = (const float*)d_in[0];
    const float* start_w = (const float*)d_in[1];
    const float* conv_w  = (const float*)d_in[2];
    const float* conv_b  = (const float*)d_in[3];
    const float* gate_w  = (const float*)d_in[4];
    const float* gate_b  = (const float*)d_in[5];
    const float* res_w   = (const float*)d_in[6];
    const float* res_b   = (const float*)d_in[7];
    const float* mixer_w = (const float*)d_in[8];
    float* out = (float*)d_out;

    // ws layout (floats):
    float* ws  = (float*)d_ws;
    float* wf  = ws;                 // 13824  packed conv weights
    float* wg  = wf + 13824;         // 13824  packed gate weights
    float* rw  = wg + 13824;         // 4352   packed res weights
    float* e0f = rw + 4352;          // 48     layer0 folded conv weights
    float* e0g = e0f + 48;           // 48
    float* hA  = e0g + 48;           // 4194304  h ping
    float* hB  = hA + 4194304;       // 4194304  h pong
    float* skip = hB + 4194304;      // 262144   running mixer accumulation
    (void)ws_size; (void)in_sizes; (void)n_in; (void)out_size;

    pack_kernel<<<72, 256, 0, stream>>>(start_w, conv_w, gate_w, res_w,
                                        wf, wg, rw, e0f, e0g);

    static const int dil[18] = {1,2,4,8,16,32,64,128,256,1,2,4,8,16,32,64,128,256};
    const int nblk = HALF / 256;   // 512 blocks

    // layer 0 (fused start conv)
    layer_kernel<0><<<nblk, 256, 0, stream>>>(
        x, start_w, nullptr, hA,
        e0f, conv_b, e0g, gate_b,
        rw, res_b, mixer_w, skip, nullptr, 1);

    float* bufs[2] = {hA, hB};
    for (int li = 1; li < 17; ++li) {
        layer_kernel<1><<<nblk, 256, 0, stream>>>(
            nullptr, nullptr, bufs[(li - 1) & 1], bufs[li & 1],
            wf + li * 768, conv_b + li * 16, wg + li * 768, gate_b + li * 16,
            rw + li * 256, res_b + li * 16, mixer_w + li * 16,
            skip, nullptr, dil[li]);
    }

    // layer 17: no residual, writes final out = skip + contribution
    layer_kernel<2><<<nblk, 256, 0, stream>>>(
        nullptr, nullptr, bufs[0], nullptr,
        wf + 17 * 768, conv_b + 17 * 16, wg + 17 * 768, gate_b + 17 * 16,
        nullptr, nullptr, mixer_w + 17 * 16,
        skip, out, dil[17]);
}